// Round 3
// baseline (15941.943 us; speedup 1.0000x reference)
//
#include <hip/hip_runtime.h>

// LSTM encoder-decoder, MI355X. B=1024, S=256, IN=8, H=512, F=96.
// Single persistent kernel: 256 wgs (1/CU), weights in VGPRs, c-state in regs,
// per-M-group device-scope sync, x folded into K-extension (K=544), fp16 MFMA.
// R2 bug fixed: A-tile staging loop covered only rows 0..31 (jj<8) -> LDS garbage
// (possible f16 NaN patterns) in rows 32..63 -> NaN out. Now jj<16 covers 64x512.

#define Hh 512
#define K2 544       // 512 h + 8 x + 24 zero pad
#define BATCH 1024
#define SEQ 256
#define FCAST 96
#define SAS 552      // LDS A stride (f16 units); 552*2=1104 B, 276 dwords -> 2-way max

typedef _Float16 f16;
typedef _Float16 f16x8 __attribute__((ext_vector_type(8)));
typedef float f32x4 __attribute__((ext_vector_type(4)));

__device__ __forceinline__ float sigf(float v) { return 1.0f / (1.0f + __expf(-v)); }
__device__ __forceinline__ float tanhf_(float v) { return 1.0f - 2.0f / (__expf(2.0f * v) + 1.0f); }

// ---------------- prep: permute + fp16-convert + fold weights ----------------
// col n (0..2047): nt=n>>7 owns units [nt*32,nt*32+32); loc=n&127 = hi*64+g*16+l4,
// unit = nt*32 + hi*16 + l4, source row r = g*512 + unit. K layout: [0,512)=Whh,
// [512,520)=Wih (enc only), [520,544)=0.
__global__ void prep_weights(const float* __restrict__ encWih, const float* __restrict__ encWhh,
                             const float* __restrict__ decWih, const float* __restrict__ decWhh,
                             const float* __restrict__ encBih, const float* __restrict__ encBhh,
                             const float* __restrict__ decBih, const float* __restrict__ decBhh,
                             const float* __restrict__ outW, const float* __restrict__ outB,
                             f16* __restrict__ encT, f16* __restrict__ decPW, f16* __restrict__ decFW,
                             float* __restrict__ bE, float* __restrict__ bP, float* __restrict__ bF) {
  int id = blockIdx.x * 256 + threadIdx.x;
  if (id >= 2048 * 68) return;
  int n = id / 68, c8 = id % 68;
  int ntt = n >> 7, loc = n & 127, hi = loc >> 6, g = (loc >> 4) & 3, l4v = loc & 15;
  int j = ntt * 32 + hi * 16 + l4v, r = g * Hh + j;
  size_t o = (size_t)n * K2 + c8 * 8;
  if (c8 < 64) {
    float dwih = decWih[r];
#pragma unroll
    for (int e = 0; e < 8; ++e) {
      int k = c8 * 8 + e;
      encT[o + e] = (f16)encWhh[(size_t)r * Hh + k];
      float dw = decWhh[(size_t)r * Hh + k];
      decPW[o + e] = (f16)dw;
      decFW[o + e] = (f16)(dw + outW[k] * dwih);
    }
  } else if (c8 == 64) {
#pragma unroll
    for (int e = 0; e < 8; ++e) {
      encT[o + e] = (f16)encWih[r * 8 + e];
      decPW[o + e] = (f16)0.f;
      decFW[o + e] = (f16)0.f;
    }
  } else {
#pragma unroll
    for (int e = 0; e < 8; ++e) {
      encT[o + e] = (f16)0.f;
      decPW[o + e] = (f16)0.f;
      decFW[o + e] = (f16)0.f;
    }
  }
  if (c8 == 0) {
    bE[n] = encBih[r] + encBhh[r];
    float bd = decBih[r] + decBhh[r];
    bP[n] = bd;
    bF[n] = bd + outB[0] * decWih[r];
  }
}

__global__ void init_state(f16* __restrict__ h0, float* __restrict__ out,
                           const float* __restrict__ outB, int* __restrict__ cnt) {
  int i = blockIdx.x * 256 + threadIdx.x;  // grid 2048 -> 524288 threads
  if (i < BATCH * Hh) h0[i] = (f16)0.f;
  if (i < BATCH * FCAST) out[i] = outB[0];
  if (i < 16 * 32) cnt[i] = 0;
}

// ---------------- persistent kernel ----------------
__global__ __launch_bounds__(256, 1) void lstm_persist(
    const f16* __restrict__ encT, const f16* __restrict__ decPW, const f16* __restrict__ decFW,
    const float* __restrict__ bE, const float* __restrict__ bP, const float* __restrict__ bF,
    const float* __restrict__ x, f16* __restrict__ h0, f16* __restrict__ h1,
    float* __restrict__ out, const float* __restrict__ outW, int* __restrict__ cnt) {
  __shared__ __align__(16) f16 sA[64 * SAS];  // 70656 B

  const int T = threadIdx.x;
  const int mt = blockIdx.x >> 4, nt = blockIdx.x & 15;
  const int m0 = mt * 64, n0 = nt * 128;
  const int w = T >> 6, lane = T & 63, l4 = lane & 15, q = lane >> 4;
  const int mw = (w & 1) * 32, nw = (w >> 1) * 64;

  f16x8 bw[4][17];   // 272 VGPRs: this wave's weight slab
  float bias_r[4];
  float cst[2][4];   // persistent c-state
#pragma unroll
  for (int a = 0; a < 2; ++a)
#pragma unroll
    for (int r = 0; r < 4; ++r) cst[a][r] = 0.f;

  int* myCnt = cnt + mt * 32;
  const int ubase = nt * 32 + (nw >> 6) * 16 + l4;  // this lane's global unit

  auto loadB = [&](const f16* WT, const float* bias) {
#pragma unroll
    for (int ct = 0; ct < 4; ++ct) {
      const f16* base = &WT[(size_t)(n0 + nw + ct * 16 + l4) * K2 + q * 8];
#pragma unroll
      for (int ks = 0; ks < 17; ++ks) bw[ct][ks] = *(const f16x8*)(base + ks * 32);
    }
#pragma unroll
    for (int g = 0; g < 4; ++g) bias_r[g] = bias[n0 + nw + g * 16 + l4];
  };

  loadB(encT, bE);
  float ow_r = 0.f;

  for (int s = 0; s < SEQ + FCAST; ++s) {
    const bool enc = s < SEQ;
    if (s == SEQ) {
      loadB(decPW, bP);          // decoder step 1: unfused (y0 = 0)
      ow_r = outW[ubase];
    } else if (s == SEQ + 1) {
      loadB(decFW, bF);          // decoder steps 2..96: feedback folded into weights
    }

    if (s > 0) {
      // release my step s-1 h-writes, then wait for whole M-group
      __builtin_amdgcn_fence(__ATOMIC_RELEASE, "agent");
      __syncthreads();
      if (T == 0) {
        atomicAdd(myCnt, 1);
        while (__hip_atomic_load(myCnt, __ATOMIC_RELAXED, __HIP_MEMORY_SCOPE_AGENT) < 16 * s)
          __builtin_amdgcn_s_sleep(1);
      }
      __syncthreads();
      __builtin_amdgcn_fence(__ATOMIC_ACQUIRE, "agent");
    }

    const f16* hin = (s & 1) ? h1 : h0;
    f16* hout = (s & 1) ? h0 : h1;

    // ---- stage A tile (64 x 512 h, + x cols for enc): 4096 f16x8 items ----
#pragma unroll
    for (int jj = 0; jj < 16; ++jj) {
      int id = T + 256 * jj;
      int row = id >> 6, kk = (id & 63) * 8;
      *(f16x8*)&sA[row * SAS + kk] = *(const f16x8*)&hin[(size_t)(m0 + row) * Hh + kk];
    }
    if (enc && T < 64) {
      const float* xp = &x[((size_t)(m0 + T) * SEQ + s) * 8];
      float4 xa = *(const float4*)xp, xb = *(const float4*)(xp + 4);
      f16x8 xv = {(f16)xa.x, (f16)xa.y, (f16)xa.z, (f16)xa.w,
                  (f16)xb.x, (f16)xb.y, (f16)xb.z, (f16)xb.w};
      f16x8 z = {(f16)0.f, (f16)0.f, (f16)0.f, (f16)0.f, (f16)0.f, (f16)0.f, (f16)0.f, (f16)0.f};
      *(f16x8*)&sA[T * SAS + 512] = xv;
      *(f16x8*)&sA[T * SAS + 520] = z;
      *(f16x8*)&sA[T * SAS + 528] = z;
      *(f16x8*)&sA[T * SAS + 536] = z;
    }
    __syncthreads();

    // ---- GEMM: acc[at][g] over K ----
    f32x4 acc[2][4];
#pragma unroll
    for (int a = 0; a < 2; ++a)
#pragma unroll
      for (int c = 0; c < 4; ++c) acc[a][c] = (f32x4){0.f, 0.f, 0.f, 0.f};

    auto innerK = [&](int ks) {
      int ko = ks * 32 + q * 8;
      f16x8 af0 = *(const f16x8*)&sA[(mw + l4) * SAS + ko];
      f16x8 af1 = *(const f16x8*)&sA[(mw + 16 + l4) * SAS + ko];
#pragma unroll
      for (int ct = 0; ct < 4; ++ct) {
        acc[0][ct] = __builtin_amdgcn_mfma_f32_16x16x32_f16(af0, bw[ct][ks], acc[0][ct], 0, 0, 0);
        acc[1][ct] = __builtin_amdgcn_mfma_f32_16x16x32_f16(af1, bw[ct][ks], acc[1][ct], 0, 0, 0);
      }
    };
    if (enc) {
#pragma unroll
      for (int ks = 0; ks < 17; ++ks) innerK(ks);
    } else {
#pragma unroll
      for (int ks = 0; ks < 16; ++ks) innerK(ks);
    }

    // ---- pointwise in-register: lane owns (rows mw+at*16+q*4+r) x unit ubase ----
#pragma unroll
    for (int at = 0; at < 2; ++at) {
#pragma unroll
      for (int r = 0; r < 4; ++r) {
        float pi = acc[at][0][r] + bias_r[0];
        float pf = acc[at][1][r] + bias_r[1];
        float pg = acc[at][2][r] + bias_r[2];
        float po = acc[at][3][r] + bias_r[3];
        float ig = sigf(pi), fg = sigf(pf), gg = tanhf_(pg), og = sigf(po);
        float cn = fg * cst[at][r] + ig * gg;
        cst[at][r] = cn;
        float hn = og * tanhf_(cn);
        int row = m0 + mw + at * 16 + q * 4 + r;
        hout[(size_t)row * Hh + ubase] = (f16)hn;
        if (!enc) {
          float pp = hn * ow_r;
          pp += __shfl_xor(pp, 1, 16);
          pp += __shfl_xor(pp, 2, 16);
          pp += __shfl_xor(pp, 4, 16);
          pp += __shfl_xor(pp, 8, 16);
          if (l4 == 0) atomicAdd(&out[row * FCAST + (s - SEQ)], pp);
        }
      }
    }
  }
}

extern "C" void kernel_launch(void* const* d_in, const int* in_sizes, int n_in, void* d_out,
                              int out_size, void* d_ws, size_t ws_size, hipStream_t stream) {
  const float* x = (const float*)d_in[0];
  const float* encWih = (const float*)d_in[1];
  const float* encWhh = (const float*)d_in[2];
  const float* encBih = (const float*)d_in[3];
  const float* encBhh = (const float*)d_in[4];
  const float* decWih = (const float*)d_in[5];
  const float* decWhh = (const float*)d_in[6];
  const float* decBih = (const float*)d_in[7];
  const float* decBhh = (const float*)d_in[8];
  const float* outW = (const float*)d_in[9];
  const float* outB = (const float*)d_in[10];
  float* out = (float*)d_out;

  char* ws = (char*)d_ws;
  f16* encT = (f16*)ws;                         // 2048*544*2 = 2228224 B
  f16* decPW = encT + 2048 * K2;
  f16* decFW = decPW + 2048 * K2;
  f16* h0 = decFW + 2048 * K2;                  // 1 MB
  f16* h1 = h0 + BATCH * Hh;                    // 1 MB
  float* bE = (float*)(h1 + BATCH * Hh);
  float* bP = bE + 2048;
  float* bF = bP + 2048;
  int* cnt = (int*)(bF + 2048);                 // 16 groups, stride 32 ints

  prep_weights<<<545, 256, 0, stream>>>(encWih, encWhh, decWih, decWhh, encBih, encBhh, decBih,
                                        decBhh, outW, outB, encT, decPW, decFW, bE, bP, bF);
  init_state<<<2048, 256, 0, stream>>>(h0, out, outB, cnt);
  lstm_persist<<<256, 256, 0, stream>>>(encT, decPW, decFW, bE, bP, bF, x, h0, h1, out, outW, cnt);
}

// Round 4
// 7137.583 us; speedup vs baseline: 2.2335x; 2.2335x over previous
//
#include <hip/hip_runtime.h>

// LSTM encoder-decoder, MI355X. B=1024, S=256, IN=8, H=512, F=96.
// Persistent kernel: 256 wgs (1/CU), weights in VGPRs, c-state in regs,
// per-M-group counter barrier. R4: h exchange via cache-BYPASSING accesses
// (relaxed agent-scope atomics -> sc0 sc1, served coherently by MALL) instead
// of per-step agent fences (buffer_wbl2/buffer_inv L2 flushes = R3's 45us/step).

#define Hh 512
#define K2 544       // 512 h + 8 x + 24 zero pad
#define BATCH 1024
#define SEQ 256
#define FCAST 96
#define SAS 552      // LDS A stride (f16 units)

typedef _Float16 f16;
typedef _Float16 f16x8 __attribute__((ext_vector_type(8)));
typedef float f32x4 __attribute__((ext_vector_type(4)));
typedef unsigned long long u64;

__device__ __forceinline__ float sigf(float v) { return 1.0f / (1.0f + __expf(-v)); }
__device__ __forceinline__ float tanhf_(float v) { return 1.0f - 2.0f / (__expf(2.0f * v) + 1.0f); }

// ---------------- prep: permute + fp16-convert + fold weights ----------------
__global__ void prep_weights(const float* __restrict__ encWih, const float* __restrict__ encWhh,
                             const float* __restrict__ decWih, const float* __restrict__ decWhh,
                             const float* __restrict__ encBih, const float* __restrict__ encBhh,
                             const float* __restrict__ decBih, const float* __restrict__ decBhh,
                             const float* __restrict__ outW, const float* __restrict__ outB,
                             f16* __restrict__ encT, f16* __restrict__ decPW, f16* __restrict__ decFW,
                             float* __restrict__ bE, float* __restrict__ bP, float* __restrict__ bF) {
  int id = blockIdx.x * 256 + threadIdx.x;
  if (id >= 2048 * 68) return;
  int n = id / 68, c8 = id % 68;
  int ntt = n >> 7, loc = n & 127, hi = loc >> 6, g = (loc >> 4) & 3, l4v = loc & 15;
  int j = ntt * 32 + hi * 16 + l4v, r = g * Hh + j;
  size_t o = (size_t)n * K2 + c8 * 8;
  if (c8 < 64) {
    float dwih = decWih[r];
#pragma unroll
    for (int e = 0; e < 8; ++e) {
      int k = c8 * 8 + e;
      encT[o + e] = (f16)encWhh[(size_t)r * Hh + k];
      float dw = decWhh[(size_t)r * Hh + k];
      decPW[o + e] = (f16)dw;
      decFW[o + e] = (f16)(dw + outW[k] * dwih);
    }
  } else if (c8 == 64) {
#pragma unroll
    for (int e = 0; e < 8; ++e) {
      encT[o + e] = (f16)encWih[r * 8 + e];
      decPW[o + e] = (f16)0.f;
      decFW[o + e] = (f16)0.f;
    }
  } else {
#pragma unroll
    for (int e = 0; e < 8; ++e) {
      encT[o + e] = (f16)0.f;
      decPW[o + e] = (f16)0.f;
      decFW[o + e] = (f16)0.f;
    }
  }
  if (c8 == 0) {
    bE[n] = encBih[r] + encBhh[r];
    float bd = decBih[r] + decBhh[r];
    bP[n] = bd;
    bF[n] = bd + outB[0] * decWih[r];
  }
}

__global__ void init_state(f16* __restrict__ h0, float* __restrict__ out,
                           const float* __restrict__ outB, int* __restrict__ cnt) {
  int i = blockIdx.x * 256 + threadIdx.x;  // grid 2048 -> 524288 threads
  if (i < BATCH * Hh) h0[i] = (f16)0.f;
  if (i < BATCH * FCAST) out[i] = outB[0];
  if (i < 16 * 32) cnt[i] = 0;
}

// ---------------- persistent kernel ----------------
__global__ __launch_bounds__(256, 1) void lstm_persist(
    const f16* __restrict__ encT, const f16* __restrict__ decPW, const f16* __restrict__ decFW,
    const float* __restrict__ bE, const float* __restrict__ bP, const float* __restrict__ bF,
    const float* __restrict__ x, f16* __restrict__ h0, f16* __restrict__ h1,
    float* __restrict__ out, const float* __restrict__ outW, int* __restrict__ cnt) {
  __shared__ __align__(16) f16 sA[64 * SAS];  // 70656 B

  const int T = threadIdx.x;
  const int mt = blockIdx.x >> 4, nt = blockIdx.x & 15;
  const int m0 = mt * 64, n0 = nt * 128;
  const int w = T >> 6, lane = T & 63, l4 = lane & 15, q = lane >> 4;
  const int mw = (w & 1) * 32, nw = (w >> 1) * 64;

  f16x8 bw[4][17];   // this wave's weight slab, resident in VGPRs
  float bias_r[4];
  float cst[2][4];   // persistent c-state
#pragma unroll
  for (int a = 0; a < 2; ++a)
#pragma unroll
    for (int r = 0; r < 4; ++r) cst[a][r] = 0.f;

  int* myCnt = cnt + mt * 32;
  const int ubase = nt * 32 + (nw >> 6) * 16 + l4;  // this lane's global unit

  auto loadB = [&](const f16* WT, const float* bias) {
#pragma unroll
    for (int ct = 0; ct < 4; ++ct) {
      const f16* base = &WT[(size_t)(n0 + nw + ct * 16 + l4) * K2 + q * 8];
#pragma unroll
      for (int ks = 0; ks < 17; ++ks) bw[ct][ks] = *(const f16x8*)(base + ks * 32);
    }
#pragma unroll
    for (int g = 0; g < 4; ++g) bias_r[g] = bias[n0 + nw + g * 16 + l4];
  };

  loadB(encT, bE);
  float ow_r = 0.f;

  for (int s = 0; s < SEQ + FCAST; ++s) {
    const bool enc = s < SEQ;
    if (s == SEQ) {
      loadB(decPW, bP);          // decoder step 1: unfused (y0 = 0)
      ow_r = outW[ubase];
    } else if (s == SEQ + 1) {
      loadB(decFW, bF);          // decoder steps 2..96: feedback folded into weights
    }

    if (s > 0) {
      // my h stores are write-through (sc0 sc1): drain them to MALL, then count in.
      asm volatile("s_waitcnt vmcnt(0)" ::: "memory");
      __syncthreads();
      if (T == 0) {
        __hip_atomic_fetch_add(myCnt, 1, __ATOMIC_RELAXED, __HIP_MEMORY_SCOPE_AGENT);
        while (__hip_atomic_load(myCnt, __ATOMIC_RELAXED, __HIP_MEMORY_SCOPE_AGENT) < 16 * s)
          __builtin_amdgcn_s_sleep(1);
      }
      __syncthreads();
      // no acquire fence: h reads below bypass L1/L2 (agent-scope atomic loads)
    }

    const f16* hin = (s & 1) ? h1 : h0;
    f16* hout = (s & 1) ? h0 : h1;

    // ---- stage A tile (64 x 512 h): 8B agent-scope loads (MALL), LDS 16B writes ----
#pragma unroll
    for (int jj = 0; jj < 16; ++jj) {
      int id = T + 256 * jj;
      int row = id >> 6, c = (id & 63) * 8;
      const u64* src = (const u64*)&hin[(size_t)(m0 + row) * Hh + c];
      u64 v0 = __hip_atomic_load(src, __ATOMIC_RELAXED, __HIP_MEMORY_SCOPE_AGENT);
      u64 v1 = __hip_atomic_load(src + 1, __ATOMIC_RELAXED, __HIP_MEMORY_SCOPE_AGENT);
      u64* dst = (u64*)&sA[row * SAS + c];
      dst[0] = v0;
      dst[1] = v1;
    }
    if (enc && T < 64) {
      const float* xp = &x[((size_t)(m0 + T) * SEQ + s) * 8];
      float4 xa = *(const float4*)xp, xb = *(const float4*)(xp + 4);
      f16x8 xv = {(f16)xa.x, (f16)xa.y, (f16)xa.z, (f16)xa.w,
                  (f16)xb.x, (f16)xb.y, (f16)xb.z, (f16)xb.w};
      f16x8 z = {(f16)0.f, (f16)0.f, (f16)0.f, (f16)0.f, (f16)0.f, (f16)0.f, (f16)0.f, (f16)0.f};
      *(f16x8*)&sA[T * SAS + 512] = xv;
      *(f16x8*)&sA[T * SAS + 520] = z;
      *(f16x8*)&sA[T * SAS + 528] = z;
      *(f16x8*)&sA[T * SAS + 536] = z;
    }
    __syncthreads();

    // ---- GEMM: acc[at][g] over K ----
    f32x4 acc[2][4];
#pragma unroll
    for (int a = 0; a < 2; ++a)
#pragma unroll
      for (int c = 0; c < 4; ++c) acc[a][c] = (f32x4){0.f, 0.f, 0.f, 0.f};

    auto innerK = [&](int ks) {
      int ko = ks * 32 + q * 8;
      f16x8 af0 = *(const f16x8*)&sA[(mw + l4) * SAS + ko];
      f16x8 af1 = *(const f16x8*)&sA[(mw + 16 + l4) * SAS + ko];
#pragma unroll
      for (int ct = 0; ct < 4; ++ct) {
        acc[0][ct] = __builtin_amdgcn_mfma_f32_16x16x32_f16(af0, bw[ct][ks], acc[0][ct], 0, 0, 0);
        acc[1][ct] = __builtin_amdgcn_mfma_f32_16x16x32_f16(af1, bw[ct][ks], acc[1][ct], 0, 0, 0);
      }
    };
    if (enc) {
#pragma unroll
      for (int ks = 0; ks < 17; ++ks) innerK(ks);
    } else {
#pragma unroll
      for (int ks = 0; ks < 16; ++ks) innerK(ks);
    }
    __syncthreads();  // done reading sA before next step's staging overwrites it

    // ---- pointwise in-register; h store = write-through agent-scope atomic ----
#pragma unroll
    for (int at = 0; at < 2; ++at) {
#pragma unroll
      for (int r = 0; r < 4; ++r) {
        float pi = acc[at][0][r] + bias_r[0];
        float pf = acc[at][1][r] + bias_r[1];
        float pg = acc[at][2][r] + bias_r[2];
        float po = acc[at][3][r] + bias_r[3];
        float ig = sigf(pi), fg = sigf(pf), gg = tanhf_(pg), og = sigf(po);
        float cn = fg * cst[at][r] + ig * gg;
        cst[at][r] = cn;
        float hn = og * tanhf_(cn);
        int row = m0 + mw + at * 16 + q * 4 + r;
        f16 hf = (f16)hn;
        unsigned short hv = *(unsigned short*)&hf;
        __hip_atomic_store((unsigned short*)&hout[(size_t)row * Hh + ubase], hv,
                           __ATOMIC_RELAXED, __HIP_MEMORY_SCOPE_AGENT);
        if (!enc) {
          float pp = hn * ow_r;
          pp += __shfl_xor(pp, 1, 16);
          pp += __shfl_xor(pp, 2, 16);
          pp += __shfl_xor(pp, 4, 16);
          pp += __shfl_xor(pp, 8, 16);
          if (l4 == 0) atomicAdd(&out[row * FCAST + (s - SEQ)], pp);
        }
      }
    }
  }
}

extern "C" void kernel_launch(void* const* d_in, const int* in_sizes, int n_in, void* d_out,
                              int out_size, void* d_ws, size_t ws_size, hipStream_t stream) {
  const float* x = (const float*)d_in[0];
  const float* encWih = (const float*)d_in[1];
  const float* encWhh = (const float*)d_in[2];
  const float* encBih = (const float*)d_in[3];
  const float* encBhh = (const float*)d_in[4];
  const float* decWih = (const float*)d_in[5];
  const float* decWhh = (const float*)d_in[6];
  const float* decBih = (const float*)d_in[7];
  const float* decBhh = (const float*)d_in[8];
  const float* outW = (const float*)d_in[9];
  const float* outB = (const float*)d_in[10];
  float* out = (float*)d_out;

  char* ws = (char*)d_ws;
  f16* encT = (f16*)ws;                         // 2048*544*2 = 2228224 B
  f16* decPW = encT + 2048 * K2;
  f16* decFW = decPW + 2048 * K2;
  f16* h0 = decFW + 2048 * K2;                  // 1 MB
  f16* h1 = h0 + BATCH * Hh;                    // 1 MB
  float* bE = (float*)(h1 + BATCH * Hh);
  float* bP = bE + 2048;
  float* bF = bP + 2048;
  int* cnt = (int*)(bF + 2048);                 // 16 groups, stride 32 ints

  prep_weights<<<545, 256, 0, stream>>>(encWih, encWhh, decWih, decWhh, encBih, encBhh, decBih,
                                        decBhh, outW, outB, encT, decPW, decFW, bE, bP, bF);
  init_state<<<2048, 256, 0, stream>>>(h0, out, outB, cnt);
  lstm_persist<<<256, 256, 0, stream>>>(encT, decPW, decFW, bE, bP, bF, x, h0, h1, out, outW, cnt);
}

// Round 5
// 4214.074 us; speedup vs baseline: 3.7830x; 1.6937x over previous
//
#include <hip/hip_runtime.h>

// LSTM encoder-decoder, MI355X. B=1024, S=256, IN=8, H=512, F=96.
// Persistent kernel, 256 wgs (1/CU). R5: XCD-self-organizing h-exchange.
//   Mode A (placement uniform, 32 wgs/XCD): M-groups are XCD-local; h moves
//     through the XCD's L2 (plain write-through stores + sc0-only loads),
//     group barrier = TCC-executed atomics (L2-local). Valid within one
//     dispatch because launch acquire invalidates L2s / end release writes back.
//   Mode B (any other placement): R4's proven agent-scope (MALL, sc0 sc1) path.
// Tiling: M=32 rows x N=256 gate-cols per wg; 32 M-groups x 8 N-slots.
// Weights in VGPRs (272/lane), c-state in regs, decoder feedback folded into
// weights (W' = Whh + out_w (x) dec_Wih), coalesced 16B h stores via LDS transpose.

#define Hh 512
#define K2 544       // 512 h + 8 x + 24 zero pad
#define BATCH 1024
#define SEQ 256
#define FCAST 96
#define Mrows 32
#define SAS 552      // sA stride (f16): 1104 B row
#define SHS 72       // sH stride (f16): 144 B row (16B-aligned, bank-skewed)

typedef _Float16 f16;
typedef _Float16 f16x8 __attribute__((ext_vector_type(8)));
typedef float f32x4 __attribute__((ext_vector_type(4)));

__device__ __forceinline__ float sigf(float v) { return 1.0f / (1.0f + __expf(-v)); }
__device__ __forceinline__ float tanhf_(float v) { return 1.0f - 2.0f / (__expf(2.0f * v) + 1.0f); }

__device__ __forceinline__ f16x8 ld16(const f16* p, bool byp) {
  f16x8 d;
  if (byp) asm volatile("global_load_dwordx4 %0, %1, off sc0 sc1" : "=v"(d) : "v"(p) : "memory");
  else     asm volatile("global_load_dwordx4 %0, %1, off sc0"     : "=v"(d) : "v"(p) : "memory");
  return d;
}
__device__ __forceinline__ void st16(f16* p, f16x8 v, bool byp) {
  if (byp) asm volatile("global_store_dwordx4 %0, %1, off sc0 sc1" :: "v"(p), "v"(v) : "memory");
  else     asm volatile("global_store_dwordx4 %0, %1, off"         :: "v"(p), "v"(v) : "memory");
}
// RMW executed at TCC (L2) — guaranteed not to be weakened to an L1-cacheable load.
__device__ __forceinline__ int atomic_add_l2(int* p, int v) {
  int old;
  asm volatile("global_atomic_add %0, %1, %2, off sc0\n\ts_waitcnt vmcnt(0)"
               : "=v"(old) : "v"(p), "v"(v) : "memory");
  return old;
}

// ---------------- prep: permute + fp16-convert + fold weights ----------------
// global col n: nslot=n>>8, wv=(n>>6)&3, g=(n>>4)&3, l4=n&15; unit=nslot*64+wv*16+l4;
// source row r = g*512 + unit. K: [0,512)=Whh, [512,520)=Wih(enc), [520,544)=0.
__global__ void prep_weights(const float* __restrict__ encWih, const float* __restrict__ encWhh,
                             const float* __restrict__ decWih, const float* __restrict__ decWhh,
                             const float* __restrict__ encBih, const float* __restrict__ encBhh,
                             const float* __restrict__ decBih, const float* __restrict__ decBhh,
                             const float* __restrict__ outW, const float* __restrict__ outB,
                             f16* __restrict__ encT, f16* __restrict__ decPW, f16* __restrict__ decFW,
                             float* __restrict__ bE, float* __restrict__ bP, float* __restrict__ bF) {
  int id = blockIdx.x * 256 + threadIdx.x;
  if (id >= 2048 * 68) return;
  int n = id / 68, c8 = id % 68;
  int nslot = n >> 8, wv = (n >> 6) & 3, g = (n >> 4) & 3, l4v = n & 15;
  int unit = nslot * 64 + wv * 16 + l4v, r = g * Hh + unit;
  size_t o = (size_t)n * K2 + c8 * 8;
  if (c8 < 64) {
    float dwih = decWih[r];
#pragma unroll
    for (int e = 0; e < 8; ++e) {
      int k = c8 * 8 + e;
      encT[o + e] = (f16)encWhh[(size_t)r * Hh + k];
      float dw = decWhh[(size_t)r * Hh + k];
      decPW[o + e] = (f16)dw;
      decFW[o + e] = (f16)(dw + outW[k] * dwih);
    }
  } else if (c8 == 64) {
#pragma unroll
    for (int e = 0; e < 8; ++e) {
      encT[o + e] = (f16)encWih[r * 8 + e];
      decPW[o + e] = (f16)0.f;
      decFW[o + e] = (f16)0.f;
    }
  } else {
#pragma unroll
    for (int e = 0; e < 8; ++e) {
      encT[o + e] = (f16)0.f;
      decPW[o + e] = (f16)0.f;
      decFW[o + e] = (f16)0.f;
    }
  }
  if (c8 == 0) {
    bE[n] = encBih[r] + encBhh[r];
    float bd = decBih[r] + decBhh[r];
    bP[n] = bd;
    bF[n] = bd + outB[0] * decWih[r];
  }
}

__global__ void init_state(f16* __restrict__ h0, float* __restrict__ out,
                           const float* __restrict__ outB, int* __restrict__ sync) {
  int i = blockIdx.x * 256 + threadIdx.x;
  if (i < BATCH * Hh) h0[i] = (f16)0.f;
  if (i < BATCH * FCAST) out[i] = outB[0];
  if (i < 2048) sync[i] = 0;   // cnt[1024] + slots[8] + arrive[1]
}

// ---------------- persistent kernel ----------------
__global__ __launch_bounds__(256, 1) void lstm_persist(
    const f16* __restrict__ encT, const f16* __restrict__ decPW, const f16* __restrict__ decFW,
    const float* __restrict__ bE, const float* __restrict__ bP, const float* __restrict__ bF,
    const float* __restrict__ x, f16* __restrict__ h0, f16* __restrict__ h1,
    float* __restrict__ out, const float* __restrict__ outW, int* __restrict__ sync) {
  __shared__ __align__(16) f16 sA[Mrows * SAS];  // 35328 B
  __shared__ __align__(16) f16 sH[Mrows * SHS];  // 4608 B
  __shared__ int sInfo[2];

  int* cnt = sync;            // 32 groups, stride 32 ints
  int* slots = sync + 1024;   // per-XCD registration
  int* arrive = sync + 1032;

  const int T = threadIdx.x;
  const int w = T >> 6, lane = T & 63, l4 = lane & 15, q = lane >> 4;

  int xcd;
  asm("s_getreg_b32 %0, hwreg(HW_REG_XCC_ID)" : "=s"(xcd));
  xcd &= 7;

  // ---- one-time self-organization (agent scope, ~µs) ----
  if (T == 0) {
    int r = __hip_atomic_fetch_add(&slots[xcd], 1, __ATOMIC_RELAXED, __HIP_MEMORY_SCOPE_AGENT);
    sInfo[0] = r;  // use of r orders slots-add before arrive-add at MALL
    __hip_atomic_fetch_add(arrive, 1, __ATOMIC_RELAXED, __HIP_MEMORY_SCOPE_AGENT);
    while (__hip_atomic_load(arrive, __ATOMIC_RELAXED, __HIP_MEMORY_SCOPE_AGENT) < 256)
      __builtin_amdgcn_s_sleep(2);
    int ok = 1;
    for (int xx = 0; xx < 8; ++xx)
      ok &= (__hip_atomic_load(&slots[xx], __ATOMIC_RELAXED, __HIP_MEMORY_SCOPE_AGENT) == 32);
    sInfo[1] = ok;
  }
  __syncthreads();
  const int rank = sInfo[0];
  const bool uni = (sInfo[1] != 0);  // identical verdict in every wg
  int group, nslot;
  if (uni) { group = xcd * 4 + (rank >> 3); nslot = rank & 7; }  // XCD-local M-group
  else     { group = (int)blockIdx.x >> 3;  nslot = (int)blockIdx.x & 7; }
  const int m0 = group * Mrows, n0 = nslot * 256, u0 = nslot * 64;
  int* myCnt = cnt + group * 32;

  f16x8 bw[4][17];   // wave's 64 gate-cols x K, resident in VGPRs
  float bias_r[4];
  float cst[2][4];
#pragma unroll
  for (int a = 0; a < 2; ++a)
#pragma unroll
    for (int r = 0; r < 4; ++r) cst[a][r] = 0.f;

  const int ubase = u0 + w * 16 + l4;  // this lane's hidden unit

  auto loadB = [&](const f16* WT, const float* bias) {
#pragma unroll
    for (int ct = 0; ct < 4; ++ct) {
      const f16* base = &WT[(size_t)(n0 + w * 64 + ct * 16 + l4) * K2 + q * 8];
#pragma unroll
      for (int ks = 0; ks < 17; ++ks) bw[ct][ks] = *(const f16x8*)(base + ks * 32);
    }
#pragma unroll
    for (int g = 0; g < 4; ++g) bias_r[g] = bias[n0 + w * 64 + g * 16 + l4];
  };

  loadB(encT, bE);
  float ow_r = 0.f;

  for (int s = 0; s < SEQ + FCAST; ++s) {
    const bool enc = s < SEQ;
    if (s == SEQ) {
      loadB(decPW, bP);
      ow_r = outW[ubase];
    } else if (s == SEQ + 1) {
      loadB(decFW, bF);
    }

    if (s > 0) {
      asm volatile("s_waitcnt vmcnt(0)" ::: "memory");  // drain my h stores (asm, untracked)
      __syncthreads();
      if (T == 0) {
        if (uni) {
          atomic_add_l2(myCnt, 1);                       // TCC RMW, XCD-local line
          while (atomic_add_l2(myCnt, 0) < 8 * s) __builtin_amdgcn_s_sleep(1);
        } else {
          __hip_atomic_fetch_add(myCnt, 1, __ATOMIC_RELAXED, __HIP_MEMORY_SCOPE_AGENT);
          while (__hip_atomic_load(myCnt, __ATOMIC_RELAXED, __HIP_MEMORY_SCOPE_AGENT) < 8 * s)
            __builtin_amdgcn_s_sleep(2);
        }
      }
      __syncthreads();
    }

    const f16* hin = (s & 1) ? h1 : h0;
    f16* hout = (s & 1) ? h0 : h1;

    // ---- stage A tile 32x512: 16B loads (mode A: L2-cached sc0; B: MALL) ----
    f16x8 d[8];
#pragma unroll
    for (int j = 0; j < 8; ++j) {
      int id = T + 256 * j;
      int row = id >> 6, c = (id & 63) * 8;
      d[j] = ld16(&hin[(size_t)(m0 + row) * Hh + c], !uni);
    }
    asm volatile("s_waitcnt vmcnt(0)" ::: "memory");
#pragma unroll
    for (int j = 0; j < 8; ++j) {
      int id = T + 256 * j;
      int row = id >> 6, c = (id & 63) * 8;
      *(f16x8*)&sA[row * SAS + c] = d[j];
    }
    if (enc && T < Mrows) {
      const float* xp = &x[((size_t)(m0 + T) * SEQ + s) * 8];
      float4 xa = *(const float4*)xp, xb = *(const float4*)(xp + 4);
      f16x8 xv = {(f16)xa.x, (f16)xa.y, (f16)xa.z, (f16)xa.w,
                  (f16)xb.x, (f16)xb.y, (f16)xb.z, (f16)xb.w};
      f16x8 z = {(f16)0.f, (f16)0.f, (f16)0.f, (f16)0.f, (f16)0.f, (f16)0.f, (f16)0.f, (f16)0.f};
      *(f16x8*)&sA[T * SAS + 512] = xv;
      *(f16x8*)&sA[T * SAS + 520] = z;
      *(f16x8*)&sA[T * SAS + 528] = z;
      *(f16x8*)&sA[T * SAS + 536] = z;
    }
    __syncthreads();

    // ---- GEMM ----
    f32x4 acc[2][4];
#pragma unroll
    for (int a = 0; a < 2; ++a)
#pragma unroll
      for (int c = 0; c < 4; ++c) acc[a][c] = (f32x4){0.f, 0.f, 0.f, 0.f};

    auto innerK = [&](int ks) {
      int ko = ks * 32 + q * 8;
      f16x8 af0 = *(const f16x8*)&sA[l4 * SAS + ko];
      f16x8 af1 = *(const f16x8*)&sA[(16 + l4) * SAS + ko];
#pragma unroll
      for (int ct = 0; ct < 4; ++ct) {
        acc[0][ct] = __builtin_amdgcn_mfma_f32_16x16x32_f16(af0, bw[ct][ks], acc[0][ct], 0, 0, 0);
        acc[1][ct] = __builtin_amdgcn_mfma_f32_16x16x32_f16(af1, bw[ct][ks], acc[1][ct], 0, 0, 0);
      }
    };
    if (enc) {
#pragma unroll
      for (int ks = 0; ks < 17; ++ks) innerK(ks);
    } else {
#pragma unroll
      for (int ks = 0; ks < 16; ++ks) innerK(ks);
    }

    // ---- pointwise in-register; h -> sH transpose ----
#pragma unroll
    for (int at = 0; at < 2; ++at) {
#pragma unroll
      for (int r = 0; r < 4; ++r) {
        float pi = acc[at][0][r] + bias_r[0];
        float pf = acc[at][1][r] + bias_r[1];
        float pg = acc[at][2][r] + bias_r[2];
        float po = acc[at][3][r] + bias_r[3];
        float ig = sigf(pi), fg = sigf(pf), gg = tanhf_(pg), og = sigf(po);
        float cn = fg * cst[at][r] + ig * gg;
        cst[at][r] = cn;
        float hn = og * tanhf_(cn);
        int row = at * 16 + q * 4 + r;
        sH[row * SHS + w * 16 + l4] = (f16)hn;
        if (!enc) {
          float pp = hn * ow_r;
          pp += __shfl_xor(pp, 1, 16);
          pp += __shfl_xor(pp, 2, 16);
          pp += __shfl_xor(pp, 4, 16);
          pp += __shfl_xor(pp, 8, 16);
          if (l4 == 0) atomicAdd(&out[(m0 + row) * FCAST + (s - SEQ)], pp);
        }
      }
    }
    __syncthreads();

    // ---- coalesced h store: 32 rows x 128 B (mode A: plain write-through to L2) ----
    {
      int row = T >> 3, seg = T & 7;
      f16x8 hv = *(const f16x8*)&sH[row * SHS + seg * 8];
      st16(&hout[(size_t)(m0 + row) * Hh + u0 + seg * 8], hv, !uni);
    }
  }
}

extern "C" void kernel_launch(void* const* d_in, const int* in_sizes, int n_in, void* d_out,
                              int out_size, void* d_ws, size_t ws_size, hipStream_t stream) {
  const float* x = (const float*)d_in[0];
  const float* encWih = (const float*)d_in[1];
  const float* encWhh = (const float*)d_in[2];
  const float* encBih = (const float*)d_in[3];
  const float* encBhh = (const float*)d_in[4];
  const float* decWih = (const float*)d_in[5];
  const float* decWhh = (const float*)d_in[6];
  const float* decBih = (const float*)d_in[7];
  const float* decBhh = (const float*)d_in[8];
  const float* outW = (const float*)d_in[9];
  const float* outB = (const float*)d_in[10];
  float* out = (float*)d_out;

  char* ws = (char*)d_ws;
  f16* encT = (f16*)ws;                         // 3 x 2048*544*2 B
  f16* decPW = encT + 2048 * K2;
  f16* decFW = decPW + 2048 * K2;
  f16* h0 = decFW + 2048 * K2;                  // 1 MB
  f16* h1 = h0 + BATCH * Hh;                    // 1 MB
  float* bE = (float*)(h1 + BATCH * Hh);
  float* bP = bE + 2048;
  float* bF = bP + 2048;
  int* sync = (int*)(bF + 2048);                // cnt[1024] slots[8] arrive[1]

  prep_weights<<<544, 256, 0, stream>>>(encWih, encWhh, decWih, decWhh, encBih, encBhh, decBih,
                                        decBhh, outW, outB, encT, decPW, decFW, bE, bP, bF);
  init_state<<<2048, 256, 0, stream>>>(h0, out, outB, sync);
  lstm_persist<<<256, 256, 0, stream>>>(encT, decPW, decFW, bE, bP, bF, x, h0, h1, out, outW, sync);
}

// Round 6
// 2627.708 us; speedup vs baseline: 6.0669x; 1.6037x over previous
//
#include <hip/hip_runtime.h>

// LSTM encoder-decoder, MI355X. B=1024, S=256, IN=8, H=512, F=96.
// Persistent kernel, 256 wgs (1/CU). R6: spill-free weight residency.
// 16 groups x 64 rows; 16 wgs/group x 128 gate-cols. Per wave bw[2][17]=136 VGPRs
// (R5's 272 forced scratch spills -> ~1KB/thread reloaded every step = the 12us/step).
// Gates (i,g)/(f,o) sit in lane pairs l4 <-> l4+8; combined via shfl_xor(8).
// Mode A: XCD-self-organized groups, h through XCD-local L2 (plain stores + sc0
// loads), barrier = TCC atomics. Mode B fallback: agent-scope MALL path.

#define Hh 512
#define K2 544       // 512 h + 8 x + 24 zero pad
#define BATCH 1024
#define SEQ 256
#define FCAST 96
#define Mrows 64
#define SAS 552      // sA stride (f16)
#define SHS 40       // sH stride (f16): 80 B row

typedef _Float16 f16;
typedef _Float16 f16x8 __attribute__((ext_vector_type(8)));
typedef float f32x4 __attribute__((ext_vector_type(4)));

__device__ __forceinline__ float sigf(float v) { return 1.0f / (1.0f + __expf(-v)); }
__device__ __forceinline__ float tanhf_(float v) { return 1.0f - 2.0f / (__expf(2.0f * v) + 1.0f); }

__device__ __forceinline__ f16x8 ld16(const f16* p, bool byp) {
  f16x8 d;
  if (byp) asm volatile("global_load_dwordx4 %0, %1, off sc0 sc1" : "=v"(d) : "v"(p) : "memory");
  else     asm volatile("global_load_dwordx4 %0, %1, off sc0"     : "=v"(d) : "v"(p) : "memory");
  return d;
}
__device__ __forceinline__ void st16(f16* p, f16x8 v, bool byp) {
  if (byp) asm volatile("global_store_dwordx4 %0, %1, off sc0 sc1" :: "v"(p), "v"(v) : "memory");
  else     asm volatile("global_store_dwordx4 %0, %1, off"         :: "v"(p), "v"(v) : "memory");
}
__device__ __forceinline__ int atomic_add_l2(int* p, int v) {
  int old;
  asm volatile("global_atomic_add %0, %1, %2, off sc0\n\ts_waitcnt vmcnt(0)"
               : "=v"(old) : "v"(p), "v"(v) : "memory");
  return old;
}

// ---------------- prep: permute + fp16-convert + fold weights ----------------
// global col n: nslot=n>>7, c=n&127, w=c>>5, cc=c&31, ct=cc>>4, l4=cc&15;
// gate=ct*2+(l4>>3), j=l4&7, unit=nslot*32+w*8+j; source row r=gate*512+unit.
// K: [0,512)=Whh, [512,520)=Wih(enc), [520,544)=0.
__global__ void prep_weights(const float* __restrict__ encWih, const float* __restrict__ encWhh,
                             const float* __restrict__ decWih, const float* __restrict__ decWhh,
                             const float* __restrict__ encBih, const float* __restrict__ encBhh,
                             const float* __restrict__ decBih, const float* __restrict__ decBhh,
                             const float* __restrict__ outW, const float* __restrict__ outB,
                             f16* __restrict__ encT, f16* __restrict__ decPW, f16* __restrict__ decFW,
                             float* __restrict__ bE, float* __restrict__ bP, float* __restrict__ bF) {
  int id = blockIdx.x * 256 + threadIdx.x;
  if (id >= 2048 * 68) return;
  int n = id / 68, c8 = id % 68;
  int nslot = n >> 7, c = n & 127, w = c >> 5, cc = c & 31, ct = cc >> 4, l4v = cc & 15;
  int g = ct * 2 + (l4v >> 3), j = l4v & 7;
  int unit = nslot * 32 + w * 8 + j, r = g * Hh + unit;
  size_t o = (size_t)n * K2 + c8 * 8;
  if (c8 < 64) {
    float dwih = decWih[r];
#pragma unroll
    for (int e = 0; e < 8; ++e) {
      int k = c8 * 8 + e;
      encT[o + e] = (f16)encWhh[(size_t)r * Hh + k];
      float dw = decWhh[(size_t)r * Hh + k];
      decPW[o + e] = (f16)dw;
      decFW[o + e] = (f16)(dw + outW[k] * dwih);
    }
  } else if (c8 == 64) {
#pragma unroll
    for (int e = 0; e < 8; ++e) {
      encT[o + e] = (f16)encWih[r * 8 + e];
      decPW[o + e] = (f16)0.f;
      decFW[o + e] = (f16)0.f;
    }
  } else {
#pragma unroll
    for (int e = 0; e < 8; ++e) {
      encT[o + e] = (f16)0.f;
      decPW[o + e] = (f16)0.f;
      decFW[o + e] = (f16)0.f;
    }
  }
  if (c8 == 0) {
    bE[n] = encBih[r] + encBhh[r];
    float bd = decBih[r] + decBhh[r];
    bP[n] = bd;
    bF[n] = bd + outB[0] * decWih[r];
  }
}

__global__ void init_state(f16* __restrict__ h0, float* __restrict__ out,
                           const float* __restrict__ outB, int* __restrict__ sync) {
  int i = blockIdx.x * 256 + threadIdx.x;
  if (i < BATCH * Hh) h0[i] = (f16)0.f;
  if (i < BATCH * FCAST) out[i] = outB[0];
  if (i < 2048) sync[i] = 0;   // cnt[16*32] + slots[8] + arrive[1]
}

// ---------------- persistent kernel ----------------
__global__ __launch_bounds__(256, 1) void lstm_persist(
    const f16* __restrict__ encT, const f16* __restrict__ decPW, const f16* __restrict__ decFW,
    const float* __restrict__ bE, const float* __restrict__ bP, const float* __restrict__ bF,
    const float* __restrict__ x, f16* __restrict__ h0, f16* __restrict__ h1,
    float* __restrict__ out, const float* __restrict__ outW, int* __restrict__ sync) {
  __shared__ __align__(16) f16 sA[Mrows * SAS];  // 70656 B
  __shared__ __align__(16) f16 sH[Mrows * SHS];  // 5120 B
  __shared__ int sInfo[2];

  int* cnt = sync;            // 16 groups, stride 32 ints
  int* slots = sync + 1024;
  int* arrive = sync + 1032;

  const int T = threadIdx.x;
  const int w = T >> 6, lane = T & 63, l4 = lane & 15, q = lane >> 4;
  const int j = l4 & 7;           // unit within wave's 8
  const bool lo = (l4 < 8);       // lo lanes own gates i,g; hi lanes f,o

  int xcd;
  asm("s_getreg_b32 %0, hwreg(HW_REG_XCC_ID)" : "=s"(xcd));
  xcd &= 7;

  // ---- one-time self-organization (agent scope) ----
  if (T == 0) {
    int r = __hip_atomic_fetch_add(&slots[xcd], 1, __ATOMIC_RELAXED, __HIP_MEMORY_SCOPE_AGENT);
    sInfo[0] = r;
    __hip_atomic_fetch_add(arrive, 1, __ATOMIC_RELAXED, __HIP_MEMORY_SCOPE_AGENT);
    while (__hip_atomic_load(arrive, __ATOMIC_RELAXED, __HIP_MEMORY_SCOPE_AGENT) < 256)
      __builtin_amdgcn_s_sleep(2);
    int ok = 1;
    for (int xx = 0; xx < 8; ++xx)
      ok &= (__hip_atomic_load(&slots[xx], __ATOMIC_RELAXED, __HIP_MEMORY_SCOPE_AGENT) == 32);
    sInfo[1] = ok;
  }
  __syncthreads();
  const int rank = sInfo[0];
  const bool uni = (sInfo[1] != 0);
  int group, nslot;
  if (uni) { group = xcd * 2 + (rank >> 4); nslot = rank & 15; }  // XCD-local group
  else     { group = (int)blockIdx.x >> 4;  nslot = (int)blockIdx.x & 15; }
  const int m0 = group * Mrows, n0 = nslot * 128, u0 = nslot * 32;
  int* myCnt = cnt + group * 32;

  f16x8 bw[2][17];   // 136 VGPRs — fits, no spill
  float bias_r[4];
  float cst[2][4];   // c-state: lo lanes rows at{0,1}, hi lanes at{2,3}
#pragma unroll
  for (int a = 0; a < 2; ++a)
#pragma unroll
    for (int r = 0; r < 4; ++r) cst[a][r] = 0.f;

  const int myUnit = u0 + w * 8 + j;

  auto loadB = [&](const f16* WT, const float* bias) {
#pragma unroll
    for (int ct = 0; ct < 2; ++ct) {
      const f16* base = &WT[(size_t)(n0 + w * 32 + ct * 16 + l4) * K2 + q * 8];
#pragma unroll
      for (int ks = 0; ks < 17; ++ks) bw[ct][ks] = *(const f16x8*)(base + ks * 32);
    }
#pragma unroll
    for (int g = 0; g < 4; ++g)
      bias_r[g] = bias[n0 + w * 32 + (g >> 1) * 16 + (g & 1) * 8 + j];
  };

  loadB(encT, bE);
  float ow_r = 0.f;

  for (int s = 0; s < SEQ + FCAST; ++s) {
    const bool enc = s < SEQ;
    if (s == SEQ) {
      loadB(decPW, bP);
      ow_r = outW[myUnit];
    } else if (s == SEQ + 1) {
      loadB(decFW, bF);
    }

    if (s > 0) {
      asm volatile("s_waitcnt vmcnt(0)" ::: "memory");
      __syncthreads();
      if (T == 0) {
        if (uni) {
          atomic_add_l2(myCnt, 1);
          while (atomic_add_l2(myCnt, 0) < 16 * s) __builtin_amdgcn_s_sleep(1);
        } else {
          __hip_atomic_fetch_add(myCnt, 1, __ATOMIC_RELAXED, __HIP_MEMORY_SCOPE_AGENT);
          while (__hip_atomic_load(myCnt, __ATOMIC_RELAXED, __HIP_MEMORY_SCOPE_AGENT) < 16 * s)
            __builtin_amdgcn_s_sleep(2);
        }
      }
      __syncthreads();
    }

    const f16* hin = (s & 1) ? h1 : h0;
    f16* hout = (s & 1) ? h0 : h1;

    // ---- stage A tile 64x512 in two batches of 8 loads/thread ----
#pragma unroll
    for (int b = 0; b < 2; ++b) {
      f16x8 d[8];
#pragma unroll
      for (int jj = 0; jj < 8; ++jj) {
        int id = T + 256 * (b * 8 + jj);
        int row = id >> 6, c8 = (id & 63) * 8;
        d[jj] = ld16(&hin[(size_t)(m0 + row) * Hh + c8], !uni);
      }
      asm volatile("s_waitcnt vmcnt(0)" ::: "memory");
#pragma unroll
      for (int jj = 0; jj < 8; ++jj) {
        int id = T + 256 * (b * 8 + jj);
        int row = id >> 6, c8 = (id & 63) * 8;
        *(f16x8*)&sA[row * SAS + c8] = d[jj];
      }
    }
    if (enc && T < Mrows) {
      const float* xp = &x[((size_t)(m0 + T) * SEQ + s) * 8];
      float4 xa = *(const float4*)xp, xb = *(const float4*)(xp + 4);
      f16x8 xv = {(f16)xa.x, (f16)xa.y, (f16)xa.z, (f16)xa.w,
                  (f16)xb.x, (f16)xb.y, (f16)xb.z, (f16)xb.w};
      f16x8 z = {(f16)0.f, (f16)0.f, (f16)0.f, (f16)0.f, (f16)0.f, (f16)0.f, (f16)0.f, (f16)0.f};
      *(f16x8*)&sA[T * SAS + 512] = xv;
      *(f16x8*)&sA[T * SAS + 520] = z;
      *(f16x8*)&sA[T * SAS + 528] = z;
      *(f16x8*)&sA[T * SAS + 536] = z;
    }
    __syncthreads();

    // ---- GEMM: 4 M-tiles x 2 N-tiles x 17 K-steps ----
    f32x4 acc[4][2];
#pragma unroll
    for (int a = 0; a < 4; ++a)
#pragma unroll
      for (int c = 0; c < 2; ++c) acc[a][c] = (f32x4){0.f, 0.f, 0.f, 0.f};

    auto innerK = [&](int ks) {
      int ko = ks * 32 + q * 8;
#pragma unroll
      for (int at = 0; at < 4; ++at) {
        f16x8 af = *(const f16x8*)&sA[(at * 16 + l4) * SAS + ko];
        acc[at][0] = __builtin_amdgcn_mfma_f32_16x16x32_f16(af, bw[0][ks], acc[at][0], 0, 0, 0);
        acc[at][1] = __builtin_amdgcn_mfma_f32_16x16x32_f16(af, bw[1][ks], acc[at][1], 0, 0, 0);
      }
    };
    if (enc) {
#pragma unroll
      for (int ks = 0; ks < 17; ++ks) innerK(ks);
    } else {
#pragma unroll
      for (int ks = 0; ks < 16; ++ks) innerK(ks);
    }

    // ---- pointwise: lane pair l4 <-> l4+8 exchanges (i,g)<->(f,o) ----
    // lo lane handles at 0..1 (rows 0..31), hi lane at 2..3 (rows 32..63).
#pragma unroll
    for (int ah = 0; ah < 2; ++ah) {
#pragma unroll
      for (int r = 0; r < 4; ++r) {
        // own at for my half; also ship my values for partner's at
        int atL = ah;          // lo's tile
        int atH = ah + 2;      // hi's tile
        float xiL = acc[atL][0][r], xgL = acc[atL][1][r];  // lo owns i,g ; hi owns f,o
        float xiH = acc[atH][0][r], xgH = acc[atH][1][r];
        float pf_recv = __shfl_xor(lo ? xiL : xiH, 8, 16);  // lo sends its atH vals? no:
        // careful: both lanes execute same shfl; choose payload so each side gets what it needs:
        // lo needs partner's acc[atL][*]; hi needs partner's acc[atH][*].
        // payload = lo ? acc[atH][...] : acc[atL][...]  (send what partner needs)
        float po_recv = 0.f;
        {
          float payload0 = lo ? xiH : xiL;   // ct=0 value partner needs
          float payload1 = lo ? xgH : xgL;   // ct=1 value partner needs
          pf_recv = __shfl_xor(payload0, 8, 16);
          po_recv = __shfl_xor(payload1, 8, 16);
        }
        // my gates: lo: i=own ct0(atL), g=own ct1(atL), f=recv0, o=recv1
        //           hi: f=own ct0(atH), o=own ct1(atH), i=recv0, g=recv1
        float gi = lo ? xiL : pf_recv;
        float gf = lo ? pf_recv : xiH;
        float gg_ = lo ? xgL : po_recv;
        float go = lo ? po_recv : xgH;
        float pi = gi + bias_r[0];
        float pf = gf + bias_r[1];
        float pg = gg_ + bias_r[2];
        float po = go + bias_r[3];
        float ig = sigf(pi), fg = sigf(pf), gg = tanhf_(pg), og = sigf(po);
        float cn = fg * cst[ah][r] + ig * gg;
        cst[ah][r] = cn;
        float hn = og * tanhf_(cn);
        int at = lo ? atL : atH;
        int row = at * 16 + q * 4 + r;
        sH[row * SHS + w * 8 + j] = (f16)hn;
        if (!enc) {
          float pp = hn * ow_r;
          pp += __shfl_xor(pp, 1, 16);
          pp += __shfl_xor(pp, 2, 16);
          pp += __shfl_xor(pp, 4, 16);
          if (j == 0) atomicAdd(&out[(m0 + row) * FCAST + (s - SEQ)], pp);
        }
      }
    }
    __syncthreads();

    // ---- coalesced h store: 64 rows x 64 B ----
    {
      int row = T >> 2, seg = T & 3;
      f16x8 hv = *(const f16x8*)&sH[row * SHS + seg * 8];
      st16(&hout[(size_t)(m0 + row) * Hh + u0 + seg * 8], hv, !uni);
    }
  }
}

extern "C" void kernel_launch(void* const* d_in, const int* in_sizes, int n_in, void* d_out,
                              int out_size, void* d_ws, size_t ws_size, hipStream_t stream) {
  const float* x = (const float*)d_in[0];
  const float* encWih = (const float*)d_in[1];
  const float* encWhh = (const float*)d_in[2];
  const float* encBih = (const float*)d_in[3];
  const float* encBhh = (const float*)d_in[4];
  const float* decWih = (const float*)d_in[5];
  const float* decWhh = (const float*)d_in[6];
  const float* decBih = (const float*)d_in[7];
  const float* decBhh = (const float*)d_in[8];
  const float* outW = (const float*)d_in[9];
  const float* outB = (const float*)d_in[10];
  float* out = (float*)d_out;

  char* ws = (char*)d_ws;
  f16* encT = (f16*)ws;
  f16* decPW = encT + 2048 * K2;
  f16* decFW = decPW + 2048 * K2;
  f16* h0 = decFW + 2048 * K2;
  f16* h1 = h0 + BATCH * Hh;
  float* bE = (float*)(h1 + BATCH * Hh);
  float* bP = bE + 2048;
  float* bF = bP + 2048;
  int* sync = (int*)(bF + 2048);

  prep_weights<<<544, 256, 0, stream>>>(encWih, encWhh, decWih, decWhh, encBih, encBhh, decBih,
                                        decBhh, outW, outB, encT, decPW, decFW, bE, bP, bF);
  init_state<<<2048, 256, 0, stream>>>(h0, out, outB, sync);
  lstm_persist<<<256, 256, 0, stream>>>(encT, decPW, decFW, bE, bP, bF, x, h0, h1, out, outW, sync);
}